// Round 1
// baseline (216.041 us; speedup 1.0000x reference)
//
#include <hip/hip_runtime.h>
#include <math.h>

#define NB 32
#define NA 5
#define NC 80
#define NH 38
#define NW 38
#define MAXT 50
#define CELLS (NH * NW)   /* 1444 */
#define CH (5 + NC)       /* 85 */
#define REC_STRIDE 12

__device__ __forceinline__ float sigmoidf_(float v) {
    return 1.0f / (1.0f + expf(-v));
}

__device__ __forceinline__ float bbox_iou_(float ax, float ay, float aw, float ah,
                                           float bx, float by, float bw, float bh) {
    float mx = fminf(ax - aw * 0.5f, bx - bw * 0.5f);
    float Mx = fmaxf(ax + aw * 0.5f, bx + bw * 0.5f);
    float my = fminf(ay - ah * 0.5f, by - bh * 0.5f);
    float My = fmaxf(ay + ah * 0.5f, by + bh * 0.5f);
    float cw = aw + bw - (Mx - mx);
    float ch = ah + bh - (My - my);
    float inter = (cw > 0.0f && ch > 0.0f) ? cw * ch : 0.0f;
    float uni = aw * ah + bw * bh - inter;
    return inter / fmaxf(uni, 1e-12f);
}

__device__ __constant__ float c_anchors[10] = {
    1.3221f, 1.73145f, 3.19275f, 4.00944f, 5.05587f,
    8.09892f, 9.47112f, 4.84053f, 11.2364f, 10.0071f};

__global__ void zero_out_kernel(float* out, int n) {
    int i = blockIdx.x * blockDim.x + threadIdx.x;
    if (i < n) out[i] = 0.0f;
}

// One block per batch, 64 threads (one wave). Thread t handles GT slot t.
// Record layout (12 floats): gx gy gw gh valid key txv tyv twv thv iou_gt pad
__global__ void prep_gt_kernel(const float* __restrict__ out,
                               const float* __restrict__ tgt,
                               float* __restrict__ recs,
                               float* __restrict__ loss) {
    const int b = blockIdx.x;
    const int t = threadIdx.x;

    __shared__ int s_nz[64];
    __shared__ int s_key[64];

    float t0 = 0.f, t1 = 0.f, gx = 0.f, gy = 0.f, gw = 0.f, gh = 0.f;
    if (t < MAXT) {
        const float* tp = tgt + (long)b * (MAXT * 5) + t * 5;
        t0 = tp[0];
        t1 = tp[1];
        gx = t1 * NW;
        gy = tp[2] * NH;
        gw = tp[3] * NW;
        gh = tp[4] * NH;
    }
    s_nz[t] = (t < MAXT) ? (t1 != 0.0f ? 1 : 0) : 1;
    __syncthreads();

    // valid = cumprod prefix: all slots 0..t nonzero
    bool valid = (t < MAXT);
    if (valid) {
        for (int u = 0; u <= t; ++u)
            if (!s_nz[u]) { valid = false; break; }
    }

    // best anchor by wh-only IoU (first tie wins, matching argmax)
    int bn = 0;
    float best = -1.0f;
    for (int a = 0; a < NA; ++a) {
        float aw = c_anchors[2 * a], ah = c_anchors[2 * a + 1];
        float inter = fminf(gw, aw) * fminf(gh, ah);
        float uni = gw * gh + aw * ah - inter;
        float iou = inter / fmaxf(uni, 1e-12f);
        if (iou > best) { best = iou; bn = a; }
    }
    int gi = (int)floorf(gx);
    gi = gi < 0 ? 0 : (gi > NW - 1 ? NW - 1 : gi);
    int gj = (int)floorf(gy);
    gj = gj < 0 ? 0 : (gj > NH - 1 ? NH - 1 : gj);

    // pred box at (b, bn, gj, gi)
    float iou_gt = 0.f, txv = 0.f, tyv = 0.f, twv = 0.f, thv = 0.f;
    if (t < MAXT) {
        long base = (((long)b * NA + bn) * CH) * CELLS + gj * NW + gi;
        float xr = out[base];
        float yr = out[base + CELLS];
        float wr = out[base + 2 * CELLS];
        float hr = out[base + 3 * CELLS];
        float px = sigmoidf_(xr) + (float)gi;
        float py = sigmoidf_(yr) + (float)gj;
        float pw = expf(wr) * c_anchors[2 * bn];
        float ph = expf(hr) * c_anchors[2 * bn + 1];
        iou_gt = bbox_iou_(gx, gy, gw, gh, px, py, pw, ph);
        txv = gx - (float)gi;
        tyv = gy - (float)gj;
        twv = logf(fmaxf(gw, 1e-12f) / c_anchors[2 * bn]);
        thv = logf(fmaxf(gh, 1e-12f) / c_anchors[2 * bn + 1]);
    }

    int key = valid ? (bn * CELLS + gj * NW + gi) : -1;
    s_key[t] = key;
    __syncthreads();

    // winner = valid and no later valid slot writes the same cell (scan overwrite)
    bool winner = valid;
    if (winner) {
        for (int u = t + 1; u < MAXT; ++u)
            if (s_key[u] == key) { winner = false; break; }
    }

    if (t < MAXT) {
        float* r = recs + ((long)b * MAXT + t) * REC_STRIDE;
        r[0] = gx; r[1] = gy; r[2] = gw; r[3] = gh;
        r[4] = valid ? 1.0f : 0.0f;
        r[5] = (float)key;
        r[6] = txv; r[7] = tyv; r[8] = twv; r[9] = thv;
        r[10] = iou_gt;
        r[11] = 0.0f;
    }

    // class loss for winner cells: -log_softmax(cls)[tcls]
    float closs = 0.0f;
    if (winner) {
        int cls = (int)t0;           // truncation, matches astype(int32)
        cls = cls < 0 ? 0 : (cls > NC - 1 ? NC - 1 : cls);
        const float* cp = out + (((long)b * NA + bn) * CH + 5) * CELLS + gj * NW + gi;
        float mx = -INFINITY;
        for (int c = 0; c < NC; ++c) mx = fmaxf(mx, cp[(long)c * CELLS]);
        float s = 0.0f;
        for (int c = 0; c < NC; ++c) s += expf(cp[(long)c * CELLS] - mx);
        float lse = mx + logf(s);
        closs = -(cp[(long)cls * CELLS] - lse);
    }
    // wave (64-lane) reduction
    for (int off = 32; off > 0; off >>= 1) closs += __shfl_down(closs, off);
    if (t == 0) atomicAdd(loss, closs);
}

// Per anchor-cell loss. grid = (ceil(NA*CELLS/256), NB)
__global__ void cell_loss_kernel(const float* __restrict__ out,
                                 const float* __restrict__ recs,
                                 float* __restrict__ loss) {
    const int b = blockIdx.y;
    const int idx = blockIdx.x * blockDim.x + threadIdx.x;

    __shared__ float sr[MAXT][REC_STRIDE];
    for (int k = threadIdx.x; k < MAXT * REC_STRIDE; k += blockDim.x)
        ((float*)sr)[k] = recs[(long)b * MAXT * REC_STRIDE + k];
    __syncthreads();

    float cell = 0.0f;
    if (idx < NA * CELLS) {
        int a = idx / CELLS;
        int r = idx - a * CELLS;
        int j = r / NW;
        int i = r - j * NW;

        long base = (((long)b * NA + a) * CH) * CELLS + r;
        float xr = out[base];
        float yr = out[base + CELLS];
        float wr = out[base + 2 * CELLS];
        float hr = out[base + 3 * CELLS];
        float cr = out[base + 4 * CELLS];

        float sx = sigmoidf_(xr);
        float sy = sigmoidf_(yr);
        float sc = sigmoidf_(cr);
        float px = sx + (float)i;
        float py = sy + (float)j;
        float pw = expf(wr) * c_anchors[2 * a];
        float ph = expf(hr) * c_anchors[2 * a + 1];

        float mykey = (float)(a * CELLS + r);
        float max_iou = 0.0f;
        int m = -1;
        #pragma unroll 5
        for (int t = 0; t < MAXT; ++t) {
            if (sr[t][4] != 0.0f) {
                float iou = bbox_iou_(sr[t][0], sr[t][1], sr[t][2], sr[t][3],
                                      px, py, pw, ph);
                max_iou = fmaxf(max_iou, iou);
                if (sr[t][5] == mykey) m = t;   // last match wins
            }
        }

        float tx = 0.5f, ty = 0.5f, tw = 0.0f, th = 0.0f, tconf = 0.0f;
        float cscale = (max_iou > 0.6f) ? 0.0f : 1.0f;   // NOOBJECT_SCALE
        if (m >= 0) {
            tx = sr[m][6]; ty = sr[m][7]; tw = sr[m][8]; th = sr[m][9];
            tconf = sr[m][10];
            cscale = 5.0f;   // OBJECT_SCALE (sqrt then squared -> scale itself)
        }
        float dx = sx - tx, dy = sy - ty, dw = wr - tw, dh = hr - th, dc = sc - tconf;
        cell = 0.5f * (dx * dx + dy * dy + dw * dw + dh * dh) + 0.5f * cscale * dc * dc;
    }

    // block reduction: wave shuffle then cross-wave LDS
    float v = cell;
    for (int off = 32; off > 0; off >>= 1) v += __shfl_down(v, off);
    __shared__ float swave[4];
    int wid = threadIdx.x >> 6;
    int lane = threadIdx.x & 63;
    if (lane == 0) swave[wid] = v;
    __syncthreads();
    if (threadIdx.x == 0) {
        float s = swave[0] + swave[1] + swave[2] + swave[3];
        atomicAdd(loss, s);
    }
}

extern "C" void kernel_launch(void* const* d_in, const int* in_sizes, int n_in,
                              void* d_out, int out_size, void* d_ws, size_t ws_size,
                              hipStream_t stream) {
    const float* output = (const float*)d_in[0];
    const float* target = (const float*)d_in[1];
    // d_in[2] = features: unused by the reference.
    float* loss = (float*)d_out;
    float* recs = (float*)d_ws;   // NB*MAXT*REC_STRIDE floats = 75 KiB

    zero_out_kernel<<<1, 64, 0, stream>>>(loss, out_size);
    prep_gt_kernel<<<NB, 64, 0, stream>>>(output, target, recs, loss);
    const int cells = NA * CELLS;                 // 7220
    dim3 grid((cells + 255) / 256, NB);
    cell_loss_kernel<<<grid, 256, 0, stream>>>(output, recs, loss);
}

// Round 3
// 206.167 us; speedup vs baseline: 1.0479x; 1.0479x over previous
//
#include <hip/hip_runtime.h>
#include <math.h>

#define NB 32
#define NA 5
#define NC 80
#define NH 38
#define NW 38
#define MAXT 50
#define CELLS (NH * NW)   /* 1444 */
#define CH (5 + NC)       /* 85 */
#define REC_STRIDE 12
#define PREP_THREADS 256
#define NWAVES (PREP_THREADS / 64)

__device__ __forceinline__ float sigmoidf_(float v) {
    return 1.0f / (1.0f + expf(-v));
}

__device__ __forceinline__ float bbox_iou_(float ax, float ay, float aw, float ah,
                                           float bx, float by, float bw, float bh) {
    float mx = fminf(ax - aw * 0.5f, bx - bw * 0.5f);
    float Mx = fmaxf(ax + aw * 0.5f, bx + bw * 0.5f);
    float my = fminf(ay - ah * 0.5f, by - bh * 0.5f);
    float My = fmaxf(ay + ah * 0.5f, by + bh * 0.5f);
    float cw = aw + bw - (Mx - mx);
    float ch = ah + bh - (My - my);
    float inter = (cw > 0.0f && ch > 0.0f) ? cw * ch : 0.0f;
    float uni = aw * ah + bw * bh - inter;
    return inter / fmaxf(uni, 1e-12f);
}

__device__ __constant__ float c_anchors[10] = {
    1.3221f, 1.73145f, 3.19275f, 4.00944f, 5.05587f,
    8.09892f, 9.47112f, 4.84053f, 11.2364f, 10.0071f};

// ws layout: recs[NB][MAXT][REC_STRIDE] floats, then cls_part[NB] floats.
#define CLS_PART_OFF (NB * MAXT * REC_STRIDE)

// Kernel 1: one block per batch, 256 threads (4 waves).
// Phase A (threads 0..63 do the work; ALL threads hit every barrier):
//   build GT records + winner flags.
// Phase B (all 4 waves): one wave per winner record computes the 80-class
// log-softmax loss with lane-parallel loads + shfl reduction.
// Block 0 also zeroes d_out (no one touches d_out until kernel 2).
__global__ void prep_gt_kernel(const float* __restrict__ out,
                               const float* __restrict__ tgt,
                               float* __restrict__ ws,
                               float* __restrict__ loss_out,
                               int out_size) {
    const int b = blockIdx.x;
    const int tid = threadIdx.x;
    const int wid = tid >> 6;
    const int lane = tid & 63;
    const int t = tid;   // GT slot for tid < MAXT

    if (b == 0) {
        for (int i = tid; i < out_size; i += PREP_THREADS) loss_out[i] = 0.0f;
    }

    __shared__ int s_nz[64];
    __shared__ int s_key[64];
    __shared__ int s_winner[MAXT];
    __shared__ int s_off[MAXT];    // per-record class-channel base offset within batch
    __shared__ int s_cls[MAXT];
    __shared__ float s_cpart[NWAVES];

    // ---- Phase A, step 1: load targets, mark nonzero ----
    float t0 = 0.f, t1 = 0.f, gx = 0.f, gy = 0.f, gw = 0.f, gh = 0.f;
    if (t < MAXT) {
        const float* tp = tgt + (long)b * (MAXT * 5) + t * 5;
        t0 = tp[0];
        t1 = tp[1];
        gx = t1 * NW;
        gy = tp[2] * NH;
        gw = tp[3] * NW;
        gh = tp[4] * NH;
    }
    if (t < 64) s_nz[t] = (t < MAXT) ? (t1 != 0.0f ? 1 : 0) : 1;
    __syncthreads();   // uniform: all 256 threads

    // ---- Phase A, step 2: valid prefix, best anchor, record build ----
    int key = -1;
    if (t < MAXT) {
        bool valid = true;
        for (int u = 0; u <= t; ++u)
            if (!s_nz[u]) { valid = false; break; }

        // best anchor (wh-only IoU, first-max wins like argmax)
        int bn = 0;
        float best = -1.0f;
        for (int a = 0; a < NA; ++a) {
            float aw = c_anchors[2 * a], ah = c_anchors[2 * a + 1];
            float inter = fminf(gw, aw) * fminf(gh, ah);
            float uni = gw * gh + aw * ah - inter;
            float iou = inter / fmaxf(uni, 1e-12f);
            if (iou > best) { best = iou; bn = a; }
        }
        int gi = (int)floorf(gx);
        gi = gi < 0 ? 0 : (gi > NW - 1 ? NW - 1 : gi);
        int gj = (int)floorf(gy);
        gj = gj < 0 ? 0 : (gj > NH - 1 ? NH - 1 : gj);

        long base = (((long)b * NA + bn) * CH) * CELLS + gj * NW + gi;
        float xr = out[base];
        float yr = out[base + CELLS];
        float wr = out[base + 2 * CELLS];
        float hr = out[base + 3 * CELLS];
        float px = sigmoidf_(xr) + (float)gi;
        float py = sigmoidf_(yr) + (float)gj;
        float pw = expf(wr) * c_anchors[2 * bn];
        float ph = expf(hr) * c_anchors[2 * bn + 1];
        float iou_gt = bbox_iou_(gx, gy, gw, gh, px, py, pw, ph);
        float txv = gx - (float)gi;
        float tyv = gy - (float)gj;
        float twv = logf(fmaxf(gw, 1e-12f) / c_anchors[2 * bn]);
        float thv = logf(fmaxf(gh, 1e-12f) / c_anchors[2 * bn + 1]);

        key = valid ? (bn * CELLS + gj * NW + gi) : -1;

        float* r = ws + ((long)b * MAXT + t) * REC_STRIDE;
        r[0] = gx; r[1] = gy; r[2] = gw; r[3] = gh;
        r[4] = valid ? 1.0f : 0.0f;
        r[5] = (float)key;
        r[6] = txv; r[7] = tyv; r[8] = twv; r[9] = thv;
        r[10] = iou_gt;
        r[11] = 0.0f;

        int cls = (int)t0;
        cls = cls < 0 ? 0 : (cls > NC - 1 ? NC - 1 : cls);
        s_cls[t] = cls;
        s_off[t] = (bn * CH + 5) * CELLS + gj * NW + gi;
    }
    if (t < 64) s_key[t] = key;
    __syncthreads();   // uniform

    // ---- Phase A, step 3: winner = valid and not overwritten by a later slot ----
    if (t < MAXT) {
        bool winner = (key >= 0);
        if (winner) {
            for (int u = t + 1; u < MAXT; ++u)
                if (s_key[u] == key) { winner = false; break; }
        }
        s_winner[t] = winner ? 1 : 0;
    }
    __syncthreads();   // uniform

    // ---- Phase B: wave-parallel class loss over winner records ----
    const float* ob = out + (long)b * NA * CH * CELLS;
    float closs = 0.0f;   // meaningful in lane 0 of each wave
    for (int rt = wid; rt < MAXT; rt += NWAVES) {
        if (!s_winner[rt]) continue;
        const float* cp = ob + s_off[rt];
        float v0 = cp[(long)lane * CELLS];                         // classes 0..63
        float v1 = (lane < NC - 64) ? cp[(long)(64 + lane) * CELLS] : -INFINITY;
        float m = fmaxf(v0, v1);
        for (int off = 32; off > 0; off >>= 1)
            m = fmaxf(m, __shfl_down(m, off));
        m = __shfl(m, 0);
        float e = expf(v0 - m) + ((lane < NC - 64) ? expf(v1 - m) : 0.0f);
        for (int off = 32; off > 0; off >>= 1)
            e += __shfl_down(e, off);
        if (lane == 0) {
            float lse = m + logf(e);
            closs += lse - cp[(long)s_cls[rt] * CELLS];
        }
    }
    if (lane == 0) s_cpart[wid] = closs;
    __syncthreads();   // uniform
    if (tid == 0) {
        float s = 0.0f;
        for (int w = 0; w < NWAVES; ++w) s += s_cpart[w];
        ws[CLS_PART_OFF + b] = s;
    }
}

// Kernel 2: per anchor-cell loss. grid = (ceil(NA*CELLS/256), NB).
// Block (0, b) also folds in the batch's class-loss partial.
__global__ void cell_loss_kernel(const float* __restrict__ out,
                                 const float* __restrict__ ws,
                                 float* __restrict__ loss) {
    const int b = blockIdx.y;
    const int idx = blockIdx.x * blockDim.x + threadIdx.x;

    __shared__ float sr[MAXT][REC_STRIDE];
    for (int k = threadIdx.x; k < MAXT * REC_STRIDE; k += blockDim.x)
        ((float*)sr)[k] = ws[(long)b * MAXT * REC_STRIDE + k];
    __syncthreads();

    float cell = 0.0f;
    if (idx < NA * CELLS) {
        int a = idx / CELLS;
        int r = idx - a * CELLS;
        int j = r / NW;
        int i = r - j * NW;

        long base = (((long)b * NA + a) * CH) * CELLS + r;
        float xr = out[base];
        float yr = out[base + CELLS];
        float wr = out[base + 2 * CELLS];
        float hr = out[base + 3 * CELLS];
        float cr = out[base + 4 * CELLS];

        float sx = sigmoidf_(xr);
        float sy = sigmoidf_(yr);
        float sc = sigmoidf_(cr);
        float px = sx + (float)i;
        float py = sy + (float)j;
        float pw = expf(wr) * c_anchors[2 * a];
        float ph = expf(hr) * c_anchors[2 * a + 1];

        float mykey = (float)(a * CELLS + r);
        float max_iou = 0.0f;
        int m = -1;
        #pragma unroll 5
        for (int t = 0; t < MAXT; ++t) {
            if (sr[t][4] != 0.0f) {
                float iou = bbox_iou_(sr[t][0], sr[t][1], sr[t][2], sr[t][3],
                                      px, py, pw, ph);
                max_iou = fmaxf(max_iou, iou);
                if (sr[t][5] == mykey) m = t;   // last match wins
            }
        }

        float tx = 0.5f, ty = 0.5f, tw = 0.0f, th = 0.0f, tconf = 0.0f;
        float cscale = (max_iou > 0.6f) ? 0.0f : 1.0f;   // NOOBJECT_SCALE
        if (m >= 0) {
            tx = sr[m][6]; ty = sr[m][7]; tw = sr[m][8]; th = sr[m][9];
            tconf = sr[m][10];
            cscale = 5.0f;   // OBJECT_SCALE
        }
        float dx = sx - tx, dy = sy - ty, dw = wr - tw, dh = hr - th, dc = sc - tconf;
        cell = 0.5f * (dx * dx + dy * dy + dw * dw + dh * dh) + 0.5f * cscale * dc * dc;
    }

    float v = cell;
    for (int off = 32; off > 0; off >>= 1) v += __shfl_down(v, off);
    __shared__ float swave[4];
    int wid = threadIdx.x >> 6;
    int lane = threadIdx.x & 63;
    if (lane == 0) swave[wid] = v;
    __syncthreads();
    if (threadIdx.x == 0) {
        float s = swave[0] + swave[1] + swave[2] + swave[3];
        if (blockIdx.x == 0) s += ws[CLS_PART_OFF + b];   // class loss partial
        atomicAdd(loss, s);
    }
}

extern "C" void kernel_launch(void* const* d_in, const int* in_sizes, int n_in,
                              void* d_out, int out_size, void* d_ws, size_t ws_size,
                              hipStream_t stream) {
    const float* output = (const float*)d_in[0];
    const float* target = (const float*)d_in[1];
    // d_in[2] = features: unused by the reference.
    float* loss = (float*)d_out;
    float* ws = (float*)d_ws;

    prep_gt_kernel<<<NB, PREP_THREADS, 0, stream>>>(output, target, ws, loss, out_size);
    const int cells = NA * CELLS;                 // 7220
    dim3 grid((cells + 255) / 256, NB);
    cell_loss_kernel<<<grid, 256, 0, stream>>>(output, ws, loss);
}

// Round 4
// 200.621 us; speedup vs baseline: 1.0769x; 1.0276x over previous
//
#include <hip/hip_runtime.h>
#include <math.h>

#define NB 32
#define NA 5
#define NC 80
#define NH 38
#define NW 38
#define MAXT 50
#define CELLS (NH * NW)   /* 1444 */
#define CH (5 + NC)       /* 85 */
#define NSLICE 8          /* blocks per batch */
#define THREADS 256
#define NWAVES (THREADS / 64)

__device__ __forceinline__ float sigmoidf_(float v) {
    return 1.0f / (1.0f + expf(-v));
}

__device__ __forceinline__ float bbox_iou_(float ax, float ay, float aw, float ah,
                                           float bx, float by, float bw, float bh) {
    float mx = fminf(ax - aw * 0.5f, bx - bw * 0.5f);
    float Mx = fmaxf(ax + aw * 0.5f, bx + bw * 0.5f);
    float my = fminf(ay - ah * 0.5f, by - bh * 0.5f);
    float My = fmaxf(ay + ah * 0.5f, by + bh * 0.5f);
    float cw = aw + bw - (Mx - mx);
    float ch = ah + bh - (My - my);
    float inter = (cw > 0.0f && ch > 0.0f) ? cw * ch : 0.0f;
    float uni = aw * ah + bw * bh - inter;
    return inter / fmaxf(uni, 1e-12f);
}

__device__ __constant__ float c_anchors[10] = {
    1.3221f, 1.73145f, 3.19275f, 4.00944f, 5.05587f,
    8.09892f, 9.47112f, 4.84053f, 11.2364f, 10.0071f};

__global__ void zero_out_kernel(float* out, int n) {
    int i = threadIdx.x;
    if (i < n) out[i] = 0.0f;
}

// Fused kernel. grid = (NSLICE, NB), 256 threads.
// Every block redundantly rebuilds its batch's 50 GT records in LDS
// (cheap, latency hidden across 1024 waves), then:
//   - grid-strides the 7220 anchor-cells of its batch (slice = blockIdx.x)
//   - each wave handles class-softmax records rt = (bx*NWAVES+wid) + 32k
// One atomicAdd per block (256 total) into the pre-zeroed d_out.
__global__ void region_loss_kernel(const float* __restrict__ out,
                                   const float* __restrict__ tgt,
                                   float* __restrict__ loss) {
    const int bx = blockIdx.x;
    const int b = blockIdx.y;
    const int tid = threadIdx.x;
    const int wid = tid >> 6;
    const int lane = tid & 63;
    const int t = tid;   // GT slot for tid < MAXT

    __shared__ int s_nz[64];
    __shared__ int s_key[64];
    __shared__ float s_rec[MAXT][12]; // gx gy gw gh valid key txv tyv twv thv iou_gt pad
    __shared__ int s_winner[MAXT];
    __shared__ int s_off[MAXT];       // class-channel base offset within batch
    __shared__ int s_cls[MAXT];
    __shared__ float s_wpart[NWAVES];

    // ---- Phase A.1: load targets, mark nonzero ----
    float t0 = 0.f, t1 = 0.f, gx = 0.f, gy = 0.f, gw = 0.f, gh = 0.f;
    if (t < MAXT) {
        const float* tp = tgt + (long)b * (MAXT * 5) + t * 5;
        t0 = tp[0];
        t1 = tp[1];
        gx = t1 * NW;
        gy = tp[2] * NH;
        gw = tp[3] * NW;
        gh = tp[4] * NH;
    }
    if (t < 64) s_nz[t] = (t < MAXT) ? (t1 != 0.0f ? 1 : 0) : 1;
    __syncthreads();

    // ---- Phase A.2: valid prefix, best anchor, record build (lanes 0..49) ----
    int key = -1;
    if (t < MAXT) {
        bool valid = true;
        for (int u = 0; u <= t; ++u)
            if (!s_nz[u]) { valid = false; break; }

        int bn = 0;
        float best = -1.0f;
        for (int a = 0; a < NA; ++a) {
            float aw = c_anchors[2 * a], ah = c_anchors[2 * a + 1];
            float inter = fminf(gw, aw) * fminf(gh, ah);
            float uni = gw * gh + aw * ah - inter;
            float iou = inter / fmaxf(uni, 1e-12f);
            if (iou > best) { best = iou; bn = a; }
        }
        int gi = (int)floorf(gx);
        gi = gi < 0 ? 0 : (gi > NW - 1 ? NW - 1 : gi);
        int gj = (int)floorf(gy);
        gj = gj < 0 ? 0 : (gj > NH - 1 ? NH - 1 : gj);

        long base = (((long)b * NA + bn) * CH) * CELLS + gj * NW + gi;
        float xr = out[base];
        float yr = out[base + CELLS];
        float wr = out[base + 2 * CELLS];
        float hr = out[base + 3 * CELLS];
        float px = sigmoidf_(xr) + (float)gi;
        float py = sigmoidf_(yr) + (float)gj;
        float pw = expf(wr) * c_anchors[2 * bn];
        float ph = expf(hr) * c_anchors[2 * bn + 1];
        float iou_gt = bbox_iou_(gx, gy, gw, gh, px, py, pw, ph);

        key = valid ? (bn * CELLS + gj * NW + gi) : -1;

        s_rec[t][0] = gx; s_rec[t][1] = gy; s_rec[t][2] = gw; s_rec[t][3] = gh;
        s_rec[t][4] = valid ? 1.0f : 0.0f;
        s_rec[t][5] = (float)key;
        s_rec[t][6] = gx - (float)gi;
        s_rec[t][7] = gy - (float)gj;
        s_rec[t][8] = logf(fmaxf(gw, 1e-12f) / c_anchors[2 * bn]);
        s_rec[t][9] = logf(fmaxf(gh, 1e-12f) / c_anchors[2 * bn + 1]);
        s_rec[t][10] = iou_gt;
        s_rec[t][11] = 0.0f;

        int cls = (int)t0;
        cls = cls < 0 ? 0 : (cls > NC - 1 ? NC - 1 : cls);
        s_cls[t] = cls;
        s_off[t] = (bn * CH + 5) * CELLS + gj * NW + gi;
    }
    if (t < 64) s_key[t] = key;
    __syncthreads();

    // ---- Phase A.3: winner = valid and not overwritten by a later slot ----
    if (t < MAXT) {
        bool winner = (key >= 0);
        if (winner) {
            for (int u = t + 1; u < MAXT; ++u)
                if (s_key[u] == key) { winner = false; break; }
        }
        s_winner[t] = winner ? 1 : 0;
    }
    __syncthreads();

    // ---- Phase B: per anchor-cell loss, grid-stride over this batch ----
    float cellsum = 0.0f;
    for (int idx = bx * THREADS + tid; idx < NA * CELLS; idx += NSLICE * THREADS) {
        int a = idx / CELLS;
        int r = idx - a * CELLS;
        int j = r / NW;
        int i = r - j * NW;

        long base = (((long)b * NA + a) * CH) * CELLS + r;
        float xr = out[base];
        float yr = out[base + CELLS];
        float wr = out[base + 2 * CELLS];
        float hr = out[base + 3 * CELLS];
        float cr = out[base + 4 * CELLS];

        float sx = sigmoidf_(xr);
        float sy = sigmoidf_(yr);
        float sc = sigmoidf_(cr);
        float px = sx + (float)i;
        float py = sy + (float)j;
        float pw = expf(wr) * c_anchors[2 * a];
        float ph = expf(hr) * c_anchors[2 * a + 1];

        float mykey = (float)(a * CELLS + r);
        float max_iou = 0.0f;
        int m = -1;
        #pragma unroll 5
        for (int u = 0; u < MAXT; ++u) {
            if (s_rec[u][4] != 0.0f) {
                float iou = bbox_iou_(s_rec[u][0], s_rec[u][1], s_rec[u][2], s_rec[u][3],
                                      px, py, pw, ph);
                max_iou = fmaxf(max_iou, iou);
                if (s_rec[u][5] == mykey) m = u;   // last match wins
            }
        }

        float tx = 0.5f, ty = 0.5f, tw = 0.0f, th = 0.0f, tconf = 0.0f;
        float cscale = (max_iou > 0.6f) ? 0.0f : 1.0f;   // NOOBJECT_SCALE
        if (m >= 0) {
            tx = s_rec[m][6]; ty = s_rec[m][7]; tw = s_rec[m][8]; th = s_rec[m][9];
            tconf = s_rec[m][10];
            cscale = 5.0f;   // OBJECT_SCALE
        }
        float dx = sx - tx, dy = sy - ty, dw = wr - tw, dh = hr - th, dc = sc - tconf;
        cellsum += 0.5f * (dx * dx + dy * dy + dw * dw + dh * dh)
                 + 0.5f * cscale * dc * dc;
    }

    // ---- Phase C: class loss; wave g handles records rt = g + 32k ----
    const float* ob = out + (long)b * NA * CH * CELLS;
    const int gwave = bx * NWAVES + wid;   // 0..31
    float closs = 0.0f;                    // lane 0 of each wave
    for (int rt = gwave; rt < MAXT; rt += NSLICE * NWAVES) {
        if (!s_winner[rt]) continue;
        const float* cp = ob + s_off[rt];
        float v0 = cp[(long)lane * CELLS];                         // classes 0..63
        float v1 = (lane < NC - 64) ? cp[(long)(64 + lane) * CELLS] : -INFINITY;
        float m = fmaxf(v0, v1);
        for (int off = 32; off > 0; off >>= 1)
            m = fmaxf(m, __shfl_down(m, off));
        m = __shfl(m, 0);
        float e = expf(v0 - m) + ((lane < NC - 64) ? expf(v1 - m) : 0.0f);
        for (int off = 32; off > 0; off >>= 1)
            e += __shfl_down(e, off);
        if (lane == 0) {
            float lse = m + logf(e);
            closs += lse - cp[(long)s_cls[rt] * CELLS];
        }
    }

    // ---- Reduction: wave shuffle + cross-wave LDS, one atomic per block ----
    float v = cellsum;
    for (int off = 32; off > 0; off >>= 1) v += __shfl_down(v, off);
    if (lane == 0) s_wpart[wid] = v + closs;
    __syncthreads();
    if (tid == 0) {
        float s = 0.0f;
        for (int w = 0; w < NWAVES; ++w) s += s_wpart[w];
        atomicAdd(loss, s);
    }
}

extern "C" void kernel_launch(void* const* d_in, const int* in_sizes, int n_in,
                              void* d_out, int out_size, void* d_ws, size_t ws_size,
                              hipStream_t stream) {
    const float* output = (const float*)d_in[0];
    const float* target = (const float*)d_in[1];
    // d_in[2] = features: unused by the reference. d_ws: unused.
    float* loss = (float*)d_out;

    zero_out_kernel<<<1, 64, 0, stream>>>(loss, out_size);
    dim3 grid(NSLICE, NB);
    region_loss_kernel<<<grid, THREADS, 0, stream>>>(output, target, loss);
}